// Round 1
// baseline (216.562 us; speedup 1.0000x reference)
//
#include <hip/hip_runtime.h>
#include <math.h>

#define BATCH 16
#define CHN   12
#define H     256
#define W     256
#define PERC_N 36
#define HID   128
#define OUTC  9   // CHN - GENE_SIZE

// One block per (batch, row). 256 threads = 256 pixels of that row.
__global__ __launch_bounds__(256, 4) void nca_kernel(
    const float* __restrict__ x, const float* __restrict__ rnd,
    const float* __restrict__ w1w, const float* __restrict__ w1b,
    const float* __restrict__ w2w, float* __restrict__ out)
{
    __shared__ float tile[CHN][3][W];   // 36 KB

    const int w = threadIdx.x;          // 0..255
    const int h = blockIdx.x & (H - 1);
    const int b = blockIdx.x >> 8;

    const int hm = (h + H - 1) & (H - 1);
    const int hp = (h + 1) & (H - 1);

    const float* xb = x + (size_t)b * CHN * H * W;

    // Stage 3 rows x 12 channels into LDS, coalesced.
    #pragma unroll
    for (int c = 0; c < CHN; ++c) {
        tile[c][0][w] = xb[(c * H + hm) * W + w];
        tile[c][1][w] = xb[(c * H + h ) * W + w];
        tile[c][2][w] = xb[(c * H + hp) * W + w];
    }
    __syncthreads();

    const int wm = (w + W - 1) & (W - 1);
    const int wp = (w + 1) & (W - 1);

    // ---- perception: x, lap, gradnorm (circular conv, correlation form) ----
    float perc[PERC_N];
    #pragma unroll
    for (int c = 0; c < CHN; ++c) {
        float a00 = tile[c][0][wm], a01 = tile[c][0][w], a02 = tile[c][0][wp];
        float a10 = tile[c][1][wm], a11 = tile[c][1][w], a12 = tile[c][1][wp];
        float a20 = tile[c][2][wm], a21 = tile[c][2][w], a22 = tile[c][2][wp];

        // SOBEL_X = [[-1,0,1],[-2,0,2],[-1,0,1]]
        float gx = (a02 - a00) + 2.f * (a12 - a10) + (a22 - a20);
        // SOBEL_X^T
        float gy = (a20 - a00) + 2.f * (a21 - a01) + (a22 - a02);
        // LAP = [[1,2,1],[2,-12,2],[1,2,1]]
        float lap = (a00 + a02 + a20 + a22)
                  + 2.f * (a01 + a10 + a12 + a21)
                  - 12.f * a11;

        perc[2 * c]     = a11;
        perc[2 * c + 1] = lap;
        perc[24 + c]    = sqrtf(gx * gx + gy * gy + 1e-8f);
    }

    // ---- life mask: 3x3 max-pool of channel 3 with CLAMPED (-inf) edges ----
    float pool = tile[3][1][w];  // center always valid
    {
        const bool hT = (h > 0), hB = (h < H - 1);
        const bool wL = (w > 0), wR = (w < W - 1);
        if (hT) {
            if (wL) pool = fmaxf(pool, tile[3][0][wm]);
                    pool = fmaxf(pool, tile[3][0][w]);
            if (wR) pool = fmaxf(pool, tile[3][0][wp]);
        }
        if (wL) pool = fmaxf(pool, tile[3][1][wm]);
        if (wR) pool = fmaxf(pool, tile[3][1][wp]);
        if (hB) {
            if (wL) pool = fmaxf(pool, tile[3][2][wm]);
                    pool = fmaxf(pool, tile[3][2][w]);
            if (wR) pool = fmaxf(pool, tile[3][2][wp]);
        }
    }
    const float life = (pool > 0.1f) ? 1.f : 0.f;
    const float mask = floorf(rnd[((size_t)b * H + h) * W + w] + 0.5f);
    const float scale = life * mask;

    // ---- per-pixel MLP: 36 -> 128 (leaky relu) -> 9 ----
    float y2[OUTC];
    #pragma unroll
    for (int o = 0; o < OUTC; ++o) y2[o] = 0.f;

    #pragma unroll 4
    for (int o = 0; o < HID; ++o) {
        const float* wr = w1w + o * PERC_N;   // uniform -> s_load
        float acc = w1b[o];
        #pragma unroll
        for (int c = 0; c < PERC_N; ++c)
            acc = fmaf(wr[c], perc[c], acc);
        // leaky relu, slope 0.01
        float y1 = fmaxf(acc, 0.f) + 0.01f * fminf(acc, 0.f);
        #pragma unroll
        for (int oo = 0; oo < OUTC; ++oo)
            y2[oo] = fmaf(w2w[oo * HID + o], y1, y2[oo]);
    }

    // ---- write output: updated 9 channels + gene passthrough ----
    float* ob = out + (size_t)b * CHN * H * W;
    #pragma unroll
    for (int o = 0; o < OUTC; ++o)
        ob[(o * H + h) * W + w] = tile[o][1][w] + y2[o] * scale;
    #pragma unroll
    for (int c = OUTC; c < CHN; ++c)
        ob[(c * H + h) * W + w] = tile[c][1][w];
}

extern "C" void kernel_launch(void* const* d_in, const int* in_sizes, int n_in,
                              void* d_out, int out_size, void* d_ws, size_t ws_size,
                              hipStream_t stream) {
    const float* x    = (const float*)d_in[0];
    const float* rnd  = (const float*)d_in[1];
    const float* w1w  = (const float*)d_in[2];
    const float* w1b  = (const float*)d_in[3];
    const float* w2w  = (const float*)d_in[4];
    float* out = (float*)d_out;

    nca_kernel<<<dim3(BATCH * H), dim3(W), 0, stream>>>(x, rnd, w1w, w1b, w2w, out);
}

// Round 2
// 94.748 us; speedup vs baseline: 2.2857x; 2.2857x over previous
//
#include <hip/hip_runtime.h>
#include <hip/hip_bf16.h>
#include <math.h>

#define CHN  12
#define H    256
#define W    256
#define HID  128
#define OUTC 9
#define KSLOTS 64

typedef __attribute__((ext_vector_type(4))) float  f32x4;
typedef __attribute__((ext_vector_type(8))) short  s16x8;
typedef __attribute__((ext_vector_type(4))) short  s16x4;
typedef __attribute__((ext_vector_type(8))) __bf16 bf16x8;

#define MFMA16x16x32(a, b, c) \
    __builtin_amdgcn_mfma_f32_16x16x32_bf16(__builtin_bit_cast(bf16x8, (a)), \
                                            __builtin_bit_cast(bf16x8, (b)), (c), 0, 0, 0)

static __device__ __forceinline__ unsigned short bfbits(float f) {
    __hip_bfloat16 h = __float2bfloat16(f);   // RNE
    return __builtin_bit_cast(unsigned short, h);
}
static __device__ __forceinline__ float bits2f(unsigned short u) {
    __hip_bfloat16 h = __builtin_bit_cast(__hip_bfloat16, u);
    return __bfloat162float(h);
}
// K-slot -> original perc column (-1 = zero pad).
// Slots 36..59 are residual-lo duplicates of lap (odd 1..23) and gradnorm (24..35).
static __device__ __forceinline__ int orig_col(int s) {
    if (s < 36) return s;
    if (s < 48) return 2 * (s - 36) + 1;
    if (s < 60) return 24 + (s - 48);
    return -1;
}

// ---------------- prologue: bake weight fragments into d_ws ----------------
// ws layout (bytes):
//   [0)      a1  : ushort [16][64][8]   (mf = m*2+f; f=0 -> k 0..31, f=1 -> k 32..63)
//   [16384)  a2h : ushort [4][64][8]
//   [20480)  a2l : ushort [4][64][8]
//   [24576)  bi  : float  [8][64][4]
__global__ void prep_weights(const float* __restrict__ w1w, const float* __restrict__ w1b,
                             const float* __restrict__ w2w, unsigned short* __restrict__ wsbuf)
{
    const int t = threadIdx.x;      // 256 threads, one block
    const int l = t & 63;
    const int grp = t >> 6;
    const int row = l & 15;
    const int g4 = l >> 4;
    unsigned short* wsa1  = wsbuf;
    unsigned short* wsa2h = wsbuf + 16 * 64 * 8;
    unsigned short* wsa2l = wsa2h + 4 * 64 * 8;
    float*          wsbi  = (float*)(wsa2l + 4 * 64 * 8);

    for (int mf = grp; mf < 16; mf += 4) {
        int m = mf >> 1, f = mf & 1;
        int hid = m * 16 + row;
        for (int j = 0; j < 8; ++j) {
            int s = f * 32 + g4 * 8 + j;
            int c = orig_col(s);
            wsa1[(mf * 64 + l) * 8 + j] = (c >= 0) ? bfbits(w1w[hid * 36 + c]) : (unsigned short)0;
        }
    }
    {
        int kb = grp;
        for (int j = 0; j < 8; ++j) {
            float wv = (row < OUTC) ? w2w[row * HID + kb * 32 + g4 * 8 + j] : 0.f;
            unsigned short hi = bfbits(wv);
            wsa2h[(kb * 64 + l) * 8 + j] = hi;
            wsa2l[(kb * 64 + l) * 8 + j] = bfbits(wv - bits2f(hi));
        }
    }
    for (int m = grp; m < 8; m += 4)
        for (int r = 0; r < 4; ++r)
            wsbi[(m * 64 + l) * 4 + r] = w1b[m * 16 + g4 * 4 + r];
}

// ---------------- main fused kernel: one block per (batch,row) ----------------
__global__ __launch_bounds__(256, 2) void nca_main(
    const float* __restrict__ x, const float* __restrict__ rnd,
    const unsigned short* __restrict__ wsbuf, float* __restrict__ out)
{
    union SMem {
        struct { float cs[CHN][W]; float dd[CHN][W]; float pr[W]; } s;  // 25 KB
        unsigned short perc[W][KSLOTS];                                 // 32 KB
    };
    __shared__ SMem sm;
    __shared__ unsigned short y1buf[4][16][HID];  // 16 KB, per-wave
    __shared__ float scale_lds[W];                // 1 KB

    const int t = threadIdx.x;
    const int h = blockIdx.x & (H - 1);
    const int b = blockIdx.x >> 8;
    const int hm = (h + H - 1) & (H - 1);
    const int hp = (h + 1) & (H - 1);
    const float* xb = x + (size_t)b * CHN * H * W;

    // ---- phase A: vertical separable pass (registers), write col sums/diffs ----
    float xc[CHN], csr[CHN], ddr[CHN];
    #pragma unroll
    for (int c = 0; c < CHN; ++c) {
        const float* xp = xb + (size_t)c * H * W;
        float v0 = xp[hm * W + t];
        float v1 = xp[h  * W + t];
        float v2 = xp[hp * W + t];
        xc[c] = v1;
        float cs = v0 + 2.f * v1 + v2;
        float dd = v2 - v0;
        csr[c] = cs; ddr[c] = dd;
        sm.s.cs[c][t] = cs;
        sm.s.dd[c][t] = dd;
        if (c == 3) {   // pool col-max, CLAMPED h-edges
            float cm = v1;
            if (h > 0)     cm = fmaxf(cm, v0);
            if (h < H - 1) cm = fmaxf(cm, v2);
            sm.s.pr[t] = cm;
        }
    }
    __syncthreads();

    // ---- phase B: horizontal pass -> perc[36], pool/life/mask ----
    const int wm = (t + W - 1) & (W - 1);
    const int wp = (t + 1) & (W - 1);
    float perc[36];
    #pragma unroll
    for (int c = 0; c < CHN; ++c) {
        float csm = sm.s.cs[c][wm], csp = sm.s.cs[c][wp];
        float ddm = sm.s.dd[c][wm], ddp = sm.s.dd[c][wp];
        float gx  = csp - csm;                              // SOBEL_X
        float gy  = ddm + 2.f * ddr[c] + ddp;               // SOBEL_X^T
        float lap = csm + 2.f * csr[c] + csp - 16.f * xc[c];
        perc[2 * c]     = xc[c];
        perc[2 * c + 1] = lap;
        perc[24 + c]    = sqrtf(gx * gx + gy * gy + 1e-8f);
    }
    {
        float pool = sm.s.pr[t];
        if (t > 0)     pool = fmaxf(pool, sm.s.pr[wm]);   // clamped w-edges
        if (t < W - 1) pool = fmaxf(pool, sm.s.pr[wp]);
        float life = (pool > 0.1f) ? 1.f : 0.f;
        float mask = floorf(rnd[((size_t)b * H + h) * W + t] + 0.5f);
        scale_lds[t] = life * mask;
    }
    const float gene0 = xc[9], gene1 = xc[10], gene2 = xc[11];
    __syncthreads();   // everyone done reading sm.s before aliasing it

    // ---- phase C: pack perc hi + residual-lo, swizzled 16B granules ----
    {
        unsigned short pb[KSLOTS];
        #pragma unroll
        for (int s = 0; s < 36; ++s) pb[s] = bfbits(perc[s]);
        #pragma unroll
        for (int s = 36; s < 60; ++s) {
            int c = orig_col(s);
            pb[s] = bfbits(perc[c] - bits2f(pb[c]));
        }
        #pragma unroll
        for (int s = 60; s < 64; ++s) pb[s] = 0;
        #pragma unroll
        for (int g = 0; g < 8; ++g) {
            s16x8 v;
            #pragma unroll
            for (int j = 0; j < 8; ++j) v[j] = (short)pb[g * 8 + j];
            *(s16x8*)&sm.perc[t][(g ^ (t & 7)) * 8] = v;
        }
    }
    // perc rows for this wave's 64 pixels were written by this same wave -> no barrier.

    // ---- phase D: load prepped weight fragments (coalesced 16B/lane) ----
    const int l = t & 63;
    const int wv = t >> 6;
    const int p16 = l & 15;
    const int g4 = l >> 4;
    const s16x8* A1  = (const s16x8*)wsbuf;   // [16][64]
    const s16x8* A2H = A1 + 16 * 64;
    const s16x8* A2L = A2H + 4 * 64;
    const f32x4* BI  = (const f32x4*)(A2L + 4 * 64);

    s16x8 a1f[16];
    #pragma unroll
    for (int mf = 0; mf < 16; ++mf) a1f[mf] = A1[mf * 64 + l];
    s16x8 a2h[4], a2l[4];
    #pragma unroll
    for (int kb = 0; kb < 4; ++kb) { a2h[kb] = A2H[kb * 64 + l]; a2l[kb] = A2L[kb * 64 + l]; }
    f32x4 binit[8];
    #pragma unroll
    for (int m = 0; m < 8; ++m) binit[m] = BI[m * 64 + l];

    // ---- phase E: per-16-pixel tile: GEMM1 -> leaky -> y1 LDS -> GEMM2 -> store ----
    #pragma unroll 1
    for (int pt = 0; pt < 4; ++pt) {
        const int p = wv * 64 + pt * 16 + p16;
        const unsigned short* prow = &sm.perc[p][0];
        const int sw = p16 & 7;
        s16x8 blo = *(const s16x8*)&prow[((g4)     ^ sw) * 8];   // k 0..31
        s16x8 bhi = *(const s16x8*)&prow[((4 + g4) ^ sw) * 8];   // k 32..63

        f32x4 acc[8];
        #pragma unroll
        for (int m = 0; m < 8; ++m) acc[m] = binit[m];
        #pragma unroll
        for (int m = 0; m < 8; ++m) {
            acc[m] = MFMA16x16x32(a1f[2 * m],     blo, acc[m]);
            acc[m] = MFMA16x16x32(a1f[2 * m + 1], bhi, acc[m]);
        }

        unsigned short* yrow = &y1buf[wv][p16][0];
        #pragma unroll
        for (int m = 0; m < 8; ++m) {
            s16x4 yv;
            #pragma unroll
            for (int r = 0; r < 4; ++r) {
                float v = acc[m][r];
                v = fmaxf(v, 0.f) + 0.01f * fminf(v, 0.f);   // leaky 0.01
                yv[r] = (short)bfbits(v);
            }
            int gw = (2 * m + (g4 >> 1)) ^ p16;
            *(s16x4*)(yrow + gw * 8 + (g4 & 1) * 4) = yv;
        }

        f32x4 acc2 = {0.f, 0.f, 0.f, 0.f};
        #pragma unroll
        for (int kb = 0; kb < 4; ++kb) {
            s16x8 b2 = *(const s16x8*)(yrow + ((kb * 4 + g4) ^ p16) * 8);
            acc2 = MFMA16x16x32(a2h[kb], b2, acc2);
            acc2 = MFMA16x16x32(a2l[kb], b2, acc2);
        }

        const float sc = scale_lds[p];
        const size_t pixbase = (size_t)b * CHN * H * W + (size_t)h * W + p;
        #pragma unroll
        for (int r = 0; r < 4; ++r) {
            int o = g4 * 4 + r;
            if (o < OUTC) {
                size_t idx = pixbase + (size_t)o * H * W;
                out[idx] = x[idx] + acc2[r] * sc;
            }
        }
    }

    // ---- gene channels passthrough ----
    {
        size_t gidx = ((size_t)b * CHN + 9) * H * W + (size_t)h * W + t;
        out[gidx]                     = gene0;
        out[gidx + (size_t)H * W]     = gene1;
        out[gidx + 2 * (size_t)H * W] = gene2;
    }
}

extern "C" void kernel_launch(void* const* d_in, const int* in_sizes, int n_in,
                              void* d_out, int out_size, void* d_ws, size_t ws_size,
                              hipStream_t stream) {
    const float* x   = (const float*)d_in[0];
    const float* rnd = (const float*)d_in[1];
    const float* w1w = (const float*)d_in[2];
    const float* w1b = (const float*)d_in[3];
    const float* w2w = (const float*)d_in[4];
    float* out = (float*)d_out;
    unsigned short* ws = (unsigned short*)d_ws;

    prep_weights<<<dim3(1), dim3(256), 0, stream>>>(w1w, w1b, w2w, ws);
    nca_main<<<dim3(16 * 256), dim3(256), 0, stream>>>(x, rnd, ws, out);
}

// Round 3
// 69.236 us; speedup vs baseline: 3.1279x; 1.3685x over previous
//
#include <hip/hip_runtime.h>
#include <hip/hip_bf16.h>
#include <math.h>

#define CHN  12
#define H    256
#define W    256
#define HID  128
#define OUTC 9
#define PSTR 72   // perc row stride in shorts (64 data + 8 pad) -> 4-bank rotation/row
#define YSTR 72   // y1 half-row stride in shorts (64 data + 8 pad)

typedef __attribute__((ext_vector_type(4))) float  f32x4;
typedef __attribute__((ext_vector_type(8))) short  s16x8;
typedef __attribute__((ext_vector_type(4))) short  s16x4;
typedef __attribute__((ext_vector_type(8))) __bf16 bf16x8;

#define MFMA16x16x32(a, b, c) \
    __builtin_amdgcn_mfma_f32_16x16x32_bf16(__builtin_bit_cast(bf16x8, (a)), \
                                            __builtin_bit_cast(bf16x8, (b)), (c), 0, 0, 0)

static __device__ __forceinline__ unsigned short bfbits(float f) {
    __hip_bfloat16 h = __float2bfloat16(f);   // RNE
    return __builtin_bit_cast(unsigned short, h);
}
static __device__ __forceinline__ float bits2f(unsigned short u) {
    __hip_bfloat16 h = __builtin_bit_cast(__hip_bfloat16, u);
    return __bfloat162float(h);
}
// K-slot -> original perc column (-1 = zero pad).
// Slots 36..59 are residual-lo duplicates of lap (odd 1..23) and gradnorm (24..35).
static __device__ __forceinline__ int orig_col(int s) {
    if (s < 36) return s;
    if (s < 48) return 2 * (s - 36) + 1;
    if (s < 60) return 24 + (s - 48);
    return -1;
}

// ---------------- prologue: bake weight fragments into d_ws ----------------
// ws layout:
//   [0)      a1  : ushort [16][64][8]   (mf = m*2+f; f=0 -> k 0..31, f=1 -> k 32..63)
//   [16384)  a2h : ushort [4][64][8]
//   [20480)  a2l : ushort [4][64][8]
//   [24576)  bi  : float  [8][64][4]
__global__ void prep_weights(const float* __restrict__ w1w, const float* __restrict__ w1b,
                             const float* __restrict__ w2w, unsigned short* __restrict__ wsbuf)
{
    const int t = threadIdx.x;      // 256 threads, one block
    const int l = t & 63;
    const int grp = t >> 6;
    const int row = l & 15;
    const int g4 = l >> 4;
    unsigned short* wsa1  = wsbuf;
    unsigned short* wsa2h = wsbuf + 16 * 64 * 8;
    unsigned short* wsa2l = wsa2h + 4 * 64 * 8;
    float*          wsbi  = (float*)(wsa2l + 4 * 64 * 8);

    for (int mf = grp; mf < 16; mf += 4) {
        int m = mf >> 1, f = mf & 1;
        int hid = m * 16 + row;
        for (int j = 0; j < 8; ++j) {
            int s = f * 32 + g4 * 8 + j;
            int c = orig_col(s);
            wsa1[(mf * 64 + l) * 8 + j] = (c >= 0) ? bfbits(w1w[hid * 36 + c]) : (unsigned short)0;
        }
    }
    {
        int kb = grp;
        for (int j = 0; j < 8; ++j) {
            float wv = (row < OUTC) ? w2w[row * HID + kb * 32 + g4 * 8 + j] : 0.f;
            unsigned short hi = bfbits(wv);
            wsa2h[(kb * 64 + l) * 8 + j] = hi;
            wsa2l[(kb * 64 + l) * 8 + j] = bfbits(wv - bits2f(hi));
        }
    }
    for (int m = grp; m < 8; m += 4)
        for (int r = 0; r < 4; ++r)
            wsbi[(m * 64 + l) * 4 + r] = w1b[m * 16 + g4 * 4 + r];
}

// ---------------- main fused kernel: one block per (batch,row) ----------------
__global__ __launch_bounds__(256, 3) void nca_main(
    const float* __restrict__ x, const float* __restrict__ rnd,
    const unsigned short* __restrict__ wsbuf, float* __restrict__ out)
{
    union SMem {
        float2 csdd[CHN][W];              // 24 KB  (cs, dd interleaved)
        unsigned short perc[W][PSTR];     // 36 KB
    };
    __shared__ SMem sm;
    __shared__ unsigned short y1h[4][16][YSTR];  // 9.2 KB, per-wave half-hid buffer
    __shared__ float prrow[W];                   // 1 KB
    __shared__ float scale_lds[W];               // 1 KB

    const int t = threadIdx.x;
    // XCD-aware bijective swizzle: XCD k gets contiguous orig ids -> halo reuse in its L2
    const int orig = ((blockIdx.x & 7) << 9) | (blockIdx.x >> 3);
    const int h = orig & (H - 1);
    const int b = orig >> 8;
    const int hm = (h + H - 1) & (H - 1);
    const int hp = (h + 1) & (H - 1);
    const float* xb = x + (size_t)b * CHN * H * W;

    // ---- phase A: vertical separable pass (registers), write col sums/diffs ----
    float xc[CHN], csr[CHN], ddr[CHN];
    const float maskraw = rnd[((size_t)b * H + h) * W + t];   // issue early
    #pragma unroll
    for (int c = 0; c < CHN; ++c) {
        const float* xp = xb + (size_t)c * H * W;
        float v0 = xp[hm * W + t];
        float v1 = xp[h  * W + t];
        float v2 = xp[hp * W + t];
        xc[c] = v1;
        float cs = fmaf(2.f, v1, v0) + v2;
        float dd = v2 - v0;
        csr[c] = cs; ddr[c] = dd;
        sm.csdd[c][t] = make_float2(cs, dd);
        if (c == 3) {   // pool col-max, CLAMPED h-edges
            float cm = v1;
            if (h > 0)     cm = fmaxf(cm, v0);
            if (h < H - 1) cm = fmaxf(cm, v2);
            prrow[t] = cm;
        }
    }
    __syncthreads();

    // ---- phase B: horizontal pass -> perc[36], pool/life/mask ----
    const int wm = (t + W - 1) & (W - 1);
    const int wp = (t + 1) & (W - 1);
    float perc[36];
    #pragma unroll
    for (int c = 0; c < CHN; ++c) {
        float2 vm = sm.csdd[c][wm];
        float2 vp = sm.csdd[c][wp];
        float gx  = vp.x - vm.x;                            // SOBEL_X
        float gy  = fmaf(2.f, ddr[c], vm.y) + vp.y;         // SOBEL_X^T
        float lap = fmaf(2.f, csr[c], vm.x + vp.x) - 16.f * xc[c];
        perc[2 * c]     = xc[c];
        perc[2 * c + 1] = lap;
        perc[24 + c]    = sqrtf(fmaf(gx, gx, gy * gy) + 1e-8f);
    }
    {
        float pool = prrow[t];
        if (t > 0)     pool = fmaxf(pool, prrow[wm]);   // clamped w-edges
        if (t < W - 1) pool = fmaxf(pool, prrow[wp]);
        float life = (pool > 0.1f) ? 1.f : 0.f;
        float mask = floorf(maskraw + 0.5f);
        scale_lds[t] = life * mask;
    }
    const float gene0 = xc[9], gene1 = xc[10], gene2 = xc[11];
    __syncthreads();   // everyone done reading sm.csdd/prrow before aliasing with perc

    // ---- phase C: pack perc hi + residual-lo, swizzled 16B granules ----
    {
        unsigned short pb[64];
        #pragma unroll
        for (int s = 0; s < 36; ++s) pb[s] = bfbits(perc[s]);
        #pragma unroll
        for (int s = 36; s < 60; ++s) {
            int c = orig_col(s);
            pb[s] = bfbits(perc[c] - bits2f(pb[c]));
        }
        #pragma unroll
        for (int s = 60; s < 64; ++s) pb[s] = 0;
        const int key_t = (t >> 3) & 7;
        #pragma unroll
        for (int g = 0; g < 8; ++g) {
            s16x8 v;
            #pragma unroll
            for (int j = 0; j < 8; ++j) v[j] = (short)pb[g * 8 + j];
            *(s16x8*)&sm.perc[t][(g ^ key_t) * 8] = v;
        }
    }
    // perc rows for this wave's 64 pixels were written by this same wave -> no barrier.

    // ---- phase D: load prepped weight fragments (coalesced 16B/lane, L2-hot) ----
    const int l = t & 63;
    const int wv = t >> 6;
    const int p16 = l & 15;
    const int g4 = l >> 4;
    const s16x8* A1  = (const s16x8*)wsbuf;   // [16][64]
    const s16x8* A2H = A1 + 16 * 64;
    const s16x8* A2L = A2H + 4 * 64;
    const f32x4* BI  = (const f32x4*)(A2L + 4 * 64);

    s16x8 a1f[16];
    #pragma unroll
    for (int mf = 0; mf < 16; ++mf) a1f[mf] = A1[mf * 64 + l];
    s16x8 a2h[4], a2l[4];
    #pragma unroll
    for (int kb = 0; kb < 4; ++kb) { a2h[kb] = A2H[kb * 64 + l]; a2l[kb] = A2L[kb * 64 + l]; }
    f32x4 binit[8];
    #pragma unroll
    for (int m = 0; m < 8; ++m) binit[m] = BI[m * 64 + l];

    // ---- phase E: per-16-pixel tile: GEMM1 -> leaky -> y1 LDS (half) -> GEMM2 -> store ----
    #pragma unroll 1
    for (int pt = 0; pt < 4; ++pt) {
        const int p = wv * 64 + pt * 16 + p16;
        const int keyp = (p >> 3) & 7;
        const unsigned short* prow = &sm.perc[p][0];
        s16x8 blo = *(const s16x8*)&prow[((0 + g4) ^ keyp) * 8];   // k 0..31
        s16x8 bhi = *(const s16x8*)&prow[((4 + g4) ^ keyp) * 8];   // k 32..63

        unsigned short* ybase = &y1h[wv][p16][0];
        f32x4 acc2 = {0.f, 0.f, 0.f, 0.f};

        #pragma unroll
        for (int hh = 0; hh < 2; ++hh) {
            // GEMM1 half: hid hh*64 .. hh*64+63
            f32x4 acc[4];
            #pragma unroll
            for (int m2 = 0; m2 < 4; ++m2) acc[m2] = binit[hh * 4 + m2];
            #pragma unroll
            for (int m2 = 0; m2 < 4; ++m2) {
                acc[m2] = MFMA16x16x32(a1f[(hh * 4 + m2) * 2],     blo, acc[m2]);
                acc[m2] = MFMA16x16x32(a1f[(hh * 4 + m2) * 2 + 1], bhi, acc[m2]);
            }
            // leaky relu (slope 0.01 < 1: exact as max(v, 0.01v)), pack to y1 half-buffer
            #pragma unroll
            for (int m2 = 0; m2 < 4; ++m2) {
                s16x4 yv;
                #pragma unroll
                for (int r = 0; r < 4; ++r) {
                    float v = acc[m2][r];
                    yv[r] = (short)bfbits(fmaxf(v, 0.01f * v));
                }
                *(s16x4*)(ybase + (2 * m2 + (g4 >> 1)) * 8 + (g4 & 1) * 4) = yv;
            }
            // GEMM2 half: kb = 2*hh + kb2
            #pragma unroll
            for (int kb2 = 0; kb2 < 2; ++kb2) {
                s16x8 b2 = *(const s16x8*)(ybase + (kb2 * 4 + g4) * 8);
                acc2 = MFMA16x16x32(a2h[hh * 2 + kb2], b2, acc2);
                acc2 = MFMA16x16x32(a2l[hh * 2 + kb2], b2, acc2);
            }
        }

        const float sc = scale_lds[p];
        const size_t pixbase = (size_t)b * CHN * H * W + (size_t)h * W + p;
        #pragma unroll
        for (int r = 0; r < 4; ++r) {
            int o = g4 * 4 + r;
            if (o < OUTC) {
                // x center (bf16-rounded) is already in blo: slot 2*o = g4*8 + 2*r
                float xhi = bits2f((unsigned short)blo[2 * r]);
                out[pixbase + (size_t)o * H * W] = fmaf(acc2[r], sc, xhi);
            }
        }
    }

    // ---- gene channels passthrough ----
    {
        size_t gidx = ((size_t)b * CHN + 9) * H * W + (size_t)h * W + t;
        out[gidx]                     = gene0;
        out[gidx + (size_t)H * W]     = gene1;
        out[gidx + 2 * (size_t)H * W] = gene2;
    }
}

extern "C" void kernel_launch(void* const* d_in, const int* in_sizes, int n_in,
                              void* d_out, int out_size, void* d_ws, size_t ws_size,
                              hipStream_t stream) {
    const float* x   = (const float*)d_in[0];
    const float* rnd = (const float*)d_in[1];
    const float* w1w = (const float*)d_in[2];
    const float* w1b = (const float*)d_in[3];
    const float* w2w = (const float*)d_in[4];
    float* out = (float*)d_out;
    unsigned short* ws = (unsigned short*)d_ws;

    prep_weights<<<dim3(1), dim3(256), 0, stream>>>(w1w, w1b, w2w, ws);
    nca_main<<<dim3(16 * 256), dim3(256), 0, stream>>>(x, rnd, ws, out);
}